// Round 2
// baseline (624.310 us; speedup 1.0000x reference)
//
#include <hip/hip_runtime.h>
#include <cstdint>

#define M_DIM 8192
#define K_DIM 4096
#define N_DIM 12288

#define BM 128
#define BN 128
#define BK 128  // int8 elements per K tile (128 bytes/row)

using i32x4 = __attribute__((ext_vector_type(4))) int;

__device__ inline void gload_lds16(const void* g, void* l) {
    __builtin_amdgcn_global_load_lds(
        (const __attribute__((address_space(1))) void*)g,
        (__attribute__((address_space(3))) void*)l,
        16, 0, 0);
}

// ---------------- weight repack: int32 (harness format) -> int8 ----------------
__global__ __launch_bounds__(256) void pack_w(const int* __restrict__ w32,
                                              int8_t* __restrict__ wq) {
    const size_t total4 = (size_t)N_DIM * K_DIM / 4;  // int4 groups
    const size_t stride = (size_t)gridDim.x * blockDim.x;
    int* out32 = (int*)wq;
    for (size_t i = (size_t)blockIdx.x * blockDim.x + threadIdx.x; i < total4;
         i += stride) {
        const int4 v = ((const int4*)w32)[i];
        out32[i] = (v.x & 255) | ((v.y & 255) << 8) | ((v.z & 255) << 16) | (v.w << 24);
    }
}

// ---------------- per-row dynamic int8 quantization ----------------
__global__ __launch_bounds__(256) void quant_rows(const float* __restrict__ x,
                                                  int8_t* __restrict__ qa,
                                                  float* __restrict__ ascale) {
    const int row = blockIdx.x;
    const int t = threadIdx.x;
    const float4* xr = (const float4*)(x + (size_t)row * K_DIM);
    float4 v[4];
    float amax = 0.0f;
#pragma unroll
    for (int c = 0; c < 4; ++c) {
        v[c] = xr[t + 256 * c];
        amax = fmaxf(amax, fmaxf(fmaxf(fabsf(v[c].x), fabsf(v[c].y)),
                                 fmaxf(fabsf(v[c].z), fabsf(v[c].w))));
    }
#pragma unroll
    for (int off = 32; off > 0; off >>= 1)
        amax = fmaxf(amax, __shfl_xor(amax, off));
    __shared__ float smax[4];
    if ((t & 63) == 0) smax[t >> 6] = amax;
    __syncthreads();
    amax = fmaxf(fmaxf(smax[0], smax[1]), fmaxf(smax[2], smax[3]));
    const float sc = amax * (1.0f / 127.0f);
    const float inv = (amax > 0.0f) ? (127.0f / amax) : 0.0f;
    if (t == 0) ascale[row] = sc;

    int* q32 = (int*)(qa + (size_t)row * K_DIM);
#pragma unroll
    for (int c = 0; c < 4; ++c) {
        int q0 = (int)rintf(v[c].x * inv);
        int q1 = (int)rintf(v[c].y * inv);
        int q2 = (int)rintf(v[c].z * inv);
        int q3 = (int)rintf(v[c].w * inv);
        q0 = min(127, max(-128, q0));
        q1 = min(127, max(-128, q1));
        q2 = min(127, max(-128, q2));
        q3 = min(127, max(-128, q3));
        q32[t + 256 * c] = (q0 & 255) | ((q1 & 255) << 8) | ((q2 & 255) << 16) | (q3 << 24);
    }
}

// ---------------- int8 GEMM + dequant epilogue ----------------
// A = qa [M,K] int8 rowmajor; B = wq [N,K] int8 rowmajor (B^T form).
// out[m,n] = acc_i32 * ascale[m] * wscale[n] + bias[n]
__global__ __launch_bounds__(256) void gemm_i8(const int8_t* __restrict__ qa,
                                               const int8_t* __restrict__ w,
                                               const float* __restrict__ ascale,
                                               const float* __restrict__ wscale,
                                               const float* __restrict__ bias,
                                               float* __restrict__ out) {
    __shared__ int8_t lA[BM * BK];  // 16 KB
    __shared__ int8_t lB[BN * BK];  // 16 KB

    const int t = threadIdx.x;
    const int bn = blockIdx.x;  // N tile
    const int bm = blockIdx.y;  // M tile
    const int lane = t & 63;
    const int wave = t >> 6;
    const int wm = wave >> 1;  // 0..1
    const int wn = wave & 1;   // 0..1
    const int lrow = lane & 15;
    const int lk = lane >> 4;  // 0..3
    const int swz = lrow & 7;

    // staging: thread t covers rows (t>>3)+32*i, 16B slot (t&7) of 8 slots/row.
    // LDS dest is linear (t*16); the XOR swizzle is applied by permuting the
    // GLOBAL source slot (involution), so swizzled reads see correct data.
    const int srow = t >> 3;   // 0..31
    const int pslot = t & 7;
    const int kslot = pslot ^ (srow & 7);

    const size_t a_base = (size_t)(bm * BM + srow) * K_DIM + (size_t)kslot * 16;
    const size_t b_base = (size_t)(bn * BN + srow) * K_DIM + (size_t)kslot * 16;

    i32x4 acc[4][4] = {};

    for (int kt = 0; kt < K_DIM / BK; ++kt) {
        const size_t koff = (size_t)kt * BK;
#pragma unroll
        for (int i = 0; i < 4; ++i)
            gload_lds16(qa + a_base + koff + (size_t)(32 * i) * K_DIM,
                        &lA[t * 16 + i * 4096]);
#pragma unroll
        for (int i = 0; i < 4; ++i)
            gload_lds16(w + b_base + koff + (size_t)(32 * i) * K_DIM,
                        &lB[t * 16 + i * 4096]);
        __syncthreads();  // compiler drains vmcnt before s_barrier

#pragma unroll
        for (int kh = 0; kh < 2; ++kh) {
            i32x4 af[4], bf[4];
#pragma unroll
            for (int m = 0; m < 4; ++m) {
                const int r = wm * 64 + m * 16 + lrow;
                af[m] = *(const i32x4*)&lA[r * BK + (((kh * 4 + lk) ^ swz) << 4)];
            }
#pragma unroll
            for (int n = 0; n < 4; ++n) {
                const int r = wn * 64 + n * 16 + lrow;
                bf[n] = *(const i32x4*)&lB[r * BK + (((kh * 4 + lk) ^ swz) << 4)];
            }
#pragma unroll
            for (int m = 0; m < 4; ++m)
#pragma unroll
                for (int n = 0; n < 4; ++n)
                    acc[m][n] = __builtin_amdgcn_mfma_i32_16x16x64_i8(
                        af[m], bf[n], acc[m][n], 0, 0, 0);
        }
        __syncthreads();  // protect LDS from next iteration's staging
    }

    // epilogue: C/D layout col = lane&15, row = (lane>>4)*4 + j
    const int r0 = bm * BM + wm * 64;
    const int c0 = bn * BN + wn * 64;
    float asc[4][4];
#pragma unroll
    for (int m = 0; m < 4; ++m)
#pragma unroll
        for (int j = 0; j < 4; ++j)
            asc[m][j] = ascale[r0 + m * 16 + lk * 4 + j];
#pragma unroll
    for (int n = 0; n < 4; ++n) {
        const int col = c0 + n * 16 + lrow;
        const float wsc = wscale[col];
        const float bb = bias[col];
#pragma unroll
        for (int m = 0; m < 4; ++m) {
#pragma unroll
            for (int j = 0; j < 4; ++j) {
                const int row = r0 + m * 16 + lk * 4 + j;
                out[(size_t)row * N_DIM + col] = (float)acc[m][n][j] * asc[m][j] * wsc + bb;
            }
        }
    }
}

extern "C" void kernel_launch(void* const* d_in, const int* in_sizes, int n_in,
                              void* d_out, int out_size, void* d_ws, size_t ws_size,
                              hipStream_t stream) {
    const float* x = (const float*)d_in[0];
    const int* w32 = (const int*)d_in[1];  // int8 weights arrive as int32
    const float* wscale = (const float*)d_in[2];
    const float* bias = (const float*)d_in[3];
    float* out = (float*)d_out;

    // workspace layout
    int8_t* qa = (int8_t*)d_ws;                                   // M*K int8
    float* ascale = (float*)((char*)d_ws + (size_t)M_DIM * K_DIM);  // M f32
    int8_t* wq = (int8_t*)((char*)d_ws + (size_t)M_DIM * K_DIM +
                           (size_t)M_DIM * sizeof(float));          // N*K int8

    pack_w<<<2048, 256, 0, stream>>>(w32, wq);
    quant_rows<<<M_DIM, 256, 0, stream>>>(x, qa, ascale);
    gemm_i8<<<dim3(N_DIM / BN, M_DIM / BM), 256, 0, stream>>>(qa, wq, ascale, wscale,
                                                              bias, out);
}

// Round 3
// 543.372 us; speedup vs baseline: 1.1490x; 1.1490x over previous
//
#include <hip/hip_runtime.h>
#include <cstdint>

#define M_DIM 8192
#define K_DIM 4096
#define N_DIM 12288
#define KTILES (K_DIM / 64)  // 64 K-tiles of BK=64 int8

using i32x4 = __attribute__((ext_vector_type(4))) int;

__device__ inline void gload_lds16(const void* g, void* l) {
    __builtin_amdgcn_global_load_lds(
        (const __attribute__((address_space(1))) void*)g,
        (__attribute__((address_space(3))) void*)l,
        16, 0, 0);
}

// ---------------- fused: per-row quant (blocks 0..M-1) + weight repack ----------------
__global__ __launch_bounds__(256) void quant_pack(const float* __restrict__ x,
                                                  const int* __restrict__ w32,
                                                  int8_t* __restrict__ qa,
                                                  float* __restrict__ ascale,
                                                  int8_t* __restrict__ wq) {
    const int t = threadIdx.x;
    if (blockIdx.x < M_DIM) {
        const int row = blockIdx.x;
        const float4* xr = (const float4*)(x + (size_t)row * K_DIM);
        float4 v[4];
        float amax = 0.0f;
#pragma unroll
        for (int c = 0; c < 4; ++c) {
            v[c] = xr[t + 256 * c];
            amax = fmaxf(amax, fmaxf(fmaxf(fabsf(v[c].x), fabsf(v[c].y)),
                                     fmaxf(fabsf(v[c].z), fabsf(v[c].w))));
        }
#pragma unroll
        for (int off = 32; off > 0; off >>= 1)
            amax = fmaxf(amax, __shfl_xor(amax, off));
        __shared__ float smax[4];
        if ((t & 63) == 0) smax[t >> 6] = amax;
        __syncthreads();
        amax = fmaxf(fmaxf(smax[0], smax[1]), fmaxf(smax[2], smax[3]));
        const float sc = amax * (1.0f / 127.0f);
        const float inv = (amax > 0.0f) ? (127.0f / amax) : 0.0f;
        if (t == 0) ascale[row] = sc;

        int* q32 = (int*)(qa + (size_t)row * K_DIM);
#pragma unroll
        for (int c = 0; c < 4; ++c) {
            int q0 = (int)rintf(v[c].x * inv);
            int q1 = (int)rintf(v[c].y * inv);
            int q2 = (int)rintf(v[c].z * inv);
            int q3 = (int)rintf(v[c].w * inv);
            q0 = min(127, max(-128, q0));
            q1 = min(127, max(-128, q1));
            q2 = min(127, max(-128, q2));
            q3 = min(127, max(-128, q3));
            q32[t + 256 * c] = (q0 & 255) | ((q1 & 255) << 8) | ((q2 & 255) << 16) | (q3 << 24);
        }
    } else {
        const int pb = blockIdx.x - M_DIM;  // 0..2047
        const size_t total4 = (size_t)N_DIM * K_DIM / 4;
        const size_t stride = (size_t)2048 * 256;
        int* out32 = (int*)wq;
        for (size_t i = (size_t)pb * 256 + t; i < total4; i += stride) {
            const int4 v = ((const int4*)w32)[i];
            out32[i] = (v.x & 255) | ((v.y & 255) << 8) | ((v.z & 255) << 16) | (v.w << 24);
        }
    }
}

// ---------------- int8 GEMM, 256x256 tile, ring-4 LDS, counted vmcnt ----------------
// A = qa [M,K] int8; B = wq [N,K] int8. out[m,n] = acc*ascale[m]*wscale[n]+bias[n]
__global__ __launch_bounds__(512, 2) void gemm_i8(const int8_t* __restrict__ qa,
                                                  const int8_t* __restrict__ wq,
                                                  const float* __restrict__ ascale,
                                                  const float* __restrict__ wscale,
                                                  const float* __restrict__ bias,
                                                  float* __restrict__ out) {
    // ring of 4 K-tile buffers; each: A[256][64] + B[256][64] int8 = 32 KB
    __shared__ int8_t lds[4][2][256 * 64];  // 128 KiB total

    const int t = threadIdx.x;
    const int lane = t & 63;
    const int wave = t >> 6;       // 0..7
    const int wm = wave >> 2;      // 0..1 -> 128 rows
    const int wn = wave & 3;       // 0..3 -> 64 cols
    const int lrow = lane & 15;
    const int lk = lane >> 4;      // 0..3
    const int elr = ((lrow ^ (lrow >> 2)) & 3);  // read-side XOR swizzle

    // XCD-aware bijective swizzle: 1536 = 8 * 192
    const int flat = blockIdx.x;
    const int sw = (flat & 7) * 192 + (flat >> 3);
    const int bm = sw / 48;  // 0..31  (M tiles)
    const int bn = sw % 48;  // 0..47  (N tiles)

    // staging: thread t covers 16B LDS slots s=t and s=t+512 of each 1024-slot
    // (256 rows x 4 slots) tile. LDS dest is linear; swizzle applied by
    // permuting the GLOBAL k-slot with the same involution the reader uses.
    const int rA0 = t >> 2;              // 0..127
    const int rA1 = (t >> 2) + 128;      // 128..255
    const int kA0 = (t & 3) ^ ((rA0 ^ (rA0 >> 2)) & 3);
    const int kA1 = (t & 3) ^ ((rA1 ^ (rA1 >> 2)) & 3);
    const size_t aoff0 = (size_t)(bm * 256 + rA0) * K_DIM + (size_t)kA0 * 16;
    const size_t aoff1 = (size_t)(bm * 256 + rA1) * K_DIM + (size_t)kA1 * 16;
    const size_t boff0 = (size_t)(bn * 256 + rA0) * K_DIM + (size_t)kA0 * 16;
    const size_t boff1 = (size_t)(bn * 256 + rA1) * K_DIM + (size_t)kA1 * 16;

    i32x4 acc[8][4] = {};

    // prologue: stage K-tiles 0 and 1 (8 loads/thread in flight)
#pragma unroll
    for (int p = 0; p < 2; ++p) {
        const size_t ko = (size_t)p * 64;
        gload_lds16(qa + aoff0 + ko, &lds[p][0][t * 16]);
        gload_lds16(qa + aoff1 + ko, &lds[p][0][t * 16 + 8192]);
        gload_lds16(wq + boff0 + ko, &lds[p][1][t * 16]);
        gload_lds16(wq + boff1 + ko, &lds[p][1][t * 16 + 8192]);
    }

    for (int j = 0; j < KTILES; ++j) {
        const int cb = j & 3;
        if (j + 2 < KTILES) {
            const int sb = (j + 2) & 3;
            const size_t ko = (size_t)(j + 2) * 64;
            gload_lds16(qa + aoff0 + ko, &lds[sb][0][t * 16]);
            gload_lds16(qa + aoff1 + ko, &lds[sb][0][t * 16 + 8192]);
            gload_lds16(wq + boff0 + ko, &lds[sb][1][t * 16]);
            gload_lds16(wq + boff1 + ko, &lds[sb][1][t * 16 + 8192]);
            asm volatile("s_waitcnt vmcnt(8)" ::: "memory");  // tile j landed; j+1,j+2 in flight
        } else if (j + 1 < KTILES) {
            asm volatile("s_waitcnt vmcnt(4)" ::: "memory");  // tile j landed; j+1 in flight
        } else {
            asm volatile("s_waitcnt vmcnt(0)" ::: "memory");  // last tile landed
        }
        __builtin_amdgcn_s_barrier();   // all waves' tile-j loads landed; also
                                        // orders reads(j-2) before STAGE(j+2) lands
        __builtin_amdgcn_sched_barrier(0);

        const int8_t* __restrict__ LA = lds[cb][0];
        const int8_t* __restrict__ LB = lds[cb][1];
        i32x4 af[8], bf[4];
#pragma unroll
        for (int m = 0; m < 8; ++m) {
            const int r = wm * 128 + m * 16 + lrow;
            af[m] = *(const i32x4*)&LA[r * 64 + ((lk ^ elr) << 4)];
        }
#pragma unroll
        for (int n = 0; n < 4; ++n) {
            const int r = wn * 64 + n * 16 + lrow;
            bf[n] = *(const i32x4*)&LB[r * 64 + ((lk ^ elr) << 4)];
        }
        __builtin_amdgcn_s_setprio(1);
#pragma unroll
        for (int m = 0; m < 8; ++m)
#pragma unroll
            for (int n = 0; n < 4; ++n)
                acc[m][n] = __builtin_amdgcn_mfma_i32_16x16x64_i8(af[m], bf[n],
                                                                  acc[m][n], 0, 0, 0);
        __builtin_amdgcn_s_setprio(0);
    }

    // epilogue: C/D layout col = lane&15, row = (lane>>4)*4 + j
    const int r0 = bm * 256 + wm * 128;
    const int c0 = bn * 256 + wn * 64;
    float asc[8][4];
#pragma unroll
    for (int m = 0; m < 8; ++m)
#pragma unroll
        for (int j = 0; j < 4; ++j)
            asc[m][j] = ascale[r0 + m * 16 + lk * 4 + j];
#pragma unroll
    for (int n = 0; n < 4; ++n) {
        const int col = c0 + n * 16 + lrow;
        const float wsc = wscale[col];
        const float bb = bias[col];
#pragma unroll
        for (int m = 0; m < 8; ++m) {
#pragma unroll
            for (int j = 0; j < 4; ++j) {
                const int row = r0 + m * 16 + lk * 4 + j;
                out[(size_t)row * N_DIM + col] = (float)acc[m][n][j] * asc[m][j] * wsc + bb;
            }
        }
    }
}

extern "C" void kernel_launch(void* const* d_in, const int* in_sizes, int n_in,
                              void* d_out, int out_size, void* d_ws, size_t ws_size,
                              hipStream_t stream) {
    const float* x = (const float*)d_in[0];
    const int* w32 = (const int*)d_in[1];  // int8 weights arrive as int32
    const float* wscale = (const float*)d_in[2];
    const float* bias = (const float*)d_in[3];
    float* out = (float*)d_out;

    int8_t* qa = (int8_t*)d_ws;                                     // M*K int8
    float* ascale = (float*)((char*)d_ws + (size_t)M_DIM * K_DIM);  // M f32
    int8_t* wq = (int8_t*)((char*)d_ws + (size_t)M_DIM * K_DIM +
                           (size_t)M_DIM * sizeof(float));          // N*K int8

    quant_pack<<<M_DIM + 2048, 256, 0, stream>>>(x, w32, qa, ascale, wq);
    gemm_i8<<<1536, 512, 0, stream>>>(qa, wq, ascale, wscale, bias, out);
}